// Round 6
// baseline (95.247 us; speedup 1.0000x reference)
//
#include <hip/hip_runtime.h>
#include <hip/hip_bf16.h>
#include <hip/hip_fp16.h>
#include <math.h>

#define N_NODES 50000
#define N_EDGES 800000
#define IN_DIM 128
#define OUT_DIM 64

typedef __attribute__((ext_vector_type(8))) short bf16x8;
typedef __attribute__((ext_vector_type(4))) float f32x4;

static __device__ __forceinline__ ushort f2bf(float f) {
  uint u = __float_as_uint(f);
  uint r = (u + 0x7fffu + ((u >> 16) & 1u)) >> 16;  // RNE
  return (ushort)r;
}
static __device__ __forceinline__ float bf2f(ushort h) {
  return __uint_as_float(((uint)h) << 16);
}

#define N4 (N_NODES / 4)            // 12500
#define SCAN_NB ((N4 + 255) / 256)  // 49
#define GEMM_NB ((N_NODES + 63) / 64)         // 782 tiles
#define E4 (N_EDGES / 4)                      // 200000 int4-groups
#define K4_T (N_EDGES / 8)                    // 100000

// ---------------------------------------------------------------------------
// K0: zero deg (tiny; a 268MB rocclr fill for this was 42us)
// ---------------------------------------------------------------------------
__global__ __launch_bounds__(256) void k0_zero(int* __restrict__ deg) {
  int i4 = blockIdx.x * 256 + threadIdx.x;
  if (i4 < N4) ((int4*)deg)[i4] = make_int4(0, 0, 0, 0);
}

// ---------------------------------------------------------------------------
// K12: GEMM blocks with per-thread rank side-duty (NOT role-split blocks —
// that starved the atomic role at 3 blocks/CU via the 48KB LDS footprint).
// Each thread: issue 4 independent atomicAdd(&deg[dst],1) FIRST, do the
// split-bf16 MFMA GEMM, store the returned ranks LAST -> atomic round-trip
// hides under staging+MFMA.
//   GEMM: h = x@W, x split hi/lo bf16, W hi-only (W-rounding err ~6e-4).
//   epilogue: h fp16 store + fused a1/a2 row-reductions.
// ---------------------------------------------------------------------------
__global__ __launch_bounds__(256) void k12_fused(
    const float* __restrict__ x, const float* __restrict__ W,
    const float* __restrict__ att, const int* __restrict__ dstp,
    __half* __restrict__ h, float* __restrict__ a1, float* __restrict__ a2,
    int* __restrict__ deg, int* __restrict__ rank) {
  __shared__ __align__(16) ushort Ah[64 * 128];
  __shared__ __align__(16) ushort Al[64 * 128];
  __shared__ __align__(16) ushort Bh[64 * 128];

  int tid = threadIdx.x;
  int row0 = blockIdx.x * 64;

  // ---- side duty: issue rank atomics early (results consumed at end) ----
  int e4 = blockIdx.x * 256 + tid;
  bool has_e = e4 < E4;
  int4 d4, r4;
  if (has_e) {
    d4 = ((const int4*)dstp)[e4];
    r4.x = atomicAdd(&deg[d4.x], 1);
    r4.y = atomicAdd(&deg[d4.y], 1);
    r4.z = atomicAdd(&deg[d4.z], 1);
    r4.w = atomicAdd(&deg[d4.w], 1);
  }

  // ---- stage x tile: 64x128 f32 = 2048 float4; 8/thread; hi/lo bf16 ----
#pragma unroll
  for (int it = 0; it < 8; ++it) {
    int i4 = it * 256 + tid;
    int row = i4 >> 5;
    int kq = i4 & 31;
    int grow = row0 + row;
    if (grow > N_NODES - 1) grow = N_NODES - 1;
    float4 v = ((const float4*)x)[(size_t)grow * 32 + kq];
    ushort4 hi, lo;
    hi.x = f2bf(v.x); lo.x = f2bf(v.x - bf2f(hi.x));
    hi.y = f2bf(v.y); lo.y = f2bf(v.y - bf2f(hi.y));
    hi.z = f2bf(v.z); lo.z = f2bf(v.z - bf2f(hi.z));
    hi.w = f2bf(v.w); lo.w = f2bf(v.w - bf2f(hi.w));
    int idx = (row * 128 + kq * 4) ^ ((row & 7) << 3);
    *(ushort4*)&Ah[idx] = hi;
    *(ushort4*)&Al[idx] = lo;
  }

  // ---- stage W transposed (hi only): BT[c][k] ----
  {
    int c = tid & 63, kq = tid >> 6;
#pragma unroll
    for (int jj = 0; jj < 4; ++jj) {
      int kb = kq * 32 + jj * 8;
      uint4 ph;
      uint hp[8];
#pragma unroll
      for (int q = 0; q < 8; ++q) hp[q] = f2bf(W[(size_t)(kb + q) * OUT_DIM + c]);
      ph.x = hp[0] | (hp[1] << 16); ph.y = hp[2] | (hp[3] << 16);
      ph.z = hp[4] | (hp[5] << 16); ph.w = hp[6] | (hp[7] << 16);
      int idx = (c * 128 + kb) ^ ((c & 7) << 3);
      *(uint4*)&Bh[idx] = ph;
    }
  }
  __syncthreads();

  int w = tid >> 6, l = tid & 63;
  int ml = l & 15, kg = l >> 4;

  f32x4 acc[4];
#pragma unroll
  for (int nt = 0; nt < 4; ++nt) acc[nt] = (f32x4){0.f, 0.f, 0.f, 0.f};

#pragma unroll
  for (int ks = 0; ks < 4; ++ks) {
    int arow = w * 16 + ml;
    int aidx = (arow * 128 + ks * 32 + kg * 8) ^ ((arow & 7) << 3);
    bf16x8 a_h = *(const bf16x8*)&Ah[aidx];
    bf16x8 a_l = *(const bf16x8*)&Al[aidx];
#pragma unroll
    for (int nt = 0; nt < 4; ++nt) {
      int brow = nt * 16 + ml;
      int bidx = (brow * 128 + ks * 32 + kg * 8) ^ ((brow & 7) << 3);
      bf16x8 b_h = *(const bf16x8*)&Bh[bidx];
      acc[nt] = __builtin_amdgcn_mfma_f32_16x16x32_bf16(a_h, b_h, acc[nt], 0, 0, 0);
      acc[nt] = __builtin_amdgcn_mfma_f32_16x16x32_bf16(a_l, b_h, acc[nt], 0, 0, 0);
    }
  }

  // ---- epilogue: C/D layout col=lane&15, row=(lane>>4)*4+reg [m89] ----
  float t1[4], t2[4];
#pragma unroll
  for (int nt = 0; nt < 4; ++nt) {
    t1[nt] = att[nt * 16 + ml];
    t2[nt] = att[OUT_DIM + nt * 16 + ml];
  }
#pragma unroll
  for (int r = 0; r < 4; ++r) {
    int drow = kg * 4 + r;
    int grow = row0 + w * 16 + drow;
    bool ok = grow < N_NODES;
    float p1 = 0.f, p2 = 0.f;
#pragma unroll
    for (int nt = 0; nt < 4; ++nt) {
      float d = acc[nt][r];
      if (ok) h[(size_t)grow * OUT_DIM + nt * 16 + ml] = __float2half(d);
      p1 = fmaf(d, t1[nt], p1);
      p2 = fmaf(d, t2[nt], p2);
    }
#pragma unroll
    for (int o = 1; o <= 8; o <<= 1) {
      p1 += __shfl_xor(p1, o, 64);
      p2 += __shfl_xor(p2, o, 64);
    }
    if (ml == 0 && ok) { a1[grow] = p1; a2[grow] = p2; }
  }

  // ---- side duty: store ranks (atomic returns have long since landed) ----
  if (has_e) ((int4*)rank)[e4] = r4;
}

// ---------------------------------------------------------------------------
// K3a: per-block scan of deg (int4); K3c: bsum scan + add + pack {off,a2}
// ---------------------------------------------------------------------------
__global__ __launch_bounds__(256) void k3a_scan(const int* __restrict__ deg,
                                                int* __restrict__ off,
                                                int* __restrict__ bsum) {
  __shared__ int sw[4];
  int tid = threadIdx.x, lane = tid & 63, wid = tid >> 6;
  int i4 = blockIdx.x * 256 + tid;
  int4 v = make_int4(0, 0, 0, 0);
  if (i4 < N4) v = ((const int4*)deg)[i4];
  int local = v.x + v.y + v.z + v.w;
  int incl = local;
#pragma unroll
  for (int o = 1; o < 64; o <<= 1) {
    int t = __shfl_up(incl, o, 64);
    if (lane >= o) incl += t;
  }
  if (lane == 63) sw[wid] = incl;
  __syncthreads();
  if (tid == 0) {
    int c = 0;
#pragma unroll
    for (int ww = 0; ww < 4; ++ww) { int t = sw[ww]; sw[ww] = c; c += t; }
    bsum[blockIdx.x] = c;
  }
  __syncthreads();
  int excl = incl - local + sw[wid];
  int4 o;
  o.x = excl; o.y = o.x + v.x; o.z = o.y + v.y; o.w = o.z + v.z;
  if (i4 < N4) ((int4*)off)[i4] = o;
}

__global__ __launch_bounds__(256) void k3c_add(int* __restrict__ off,
                                               const int* __restrict__ bsum,
                                               const float* __restrict__ a2,
                                               int2* __restrict__ oa2) {
  __shared__ int sb[64];
  int tid = threadIdx.x;
  if (tid < 64) {
    int v = (tid < SCAN_NB) ? bsum[tid] : 0;
    int incl = v;
#pragma unroll
    for (int o = 1; o < 64; o <<= 1) {
      int t = __shfl_up(incl, o, 64);
      if (tid >= o) incl += t;
    }
    sb[tid] = incl - v;  // exclusive block prefix
  }
  __syncthreads();
  int i4 = blockIdx.x * 256 + tid;
  if (i4 == 0) off[N_NODES] = N_EDGES;
  if (i4 >= N4) return;
  int add = sb[blockIdx.x];
  int4 v = ((const int4*)off)[i4];
  v.x += add; v.y += add; v.z += add; v.w += add;
  ((int4*)off)[i4] = v;
  float4 a = ((const float4*)a2)[i4];
  int4 p0 = make_int4(v.x, __float_as_int(a.x), v.y, __float_as_int(a.y));
  int4 p1 = make_int4(v.z, __float_as_int(a.z), v.w, __float_as_int(a.w));
  ((int4*)oa2)[i4 * 2] = p0;
  ((int4*)oa2)[i4 * 2 + 1] = p1;
}

// ---------------------------------------------------------------------------
// K4: atomic-free scatter, 8 edges/thread (8 independent gather->store chains)
// sedge[off[d]+rank] = {src, exp(leaky(a1+a2))}
// ---------------------------------------------------------------------------
__global__ __launch_bounds__(256) void k4_scatter(
    const int* __restrict__ src, const int* __restrict__ dstp,
    const int* __restrict__ rank,
    const float* __restrict__ a1, const int2* __restrict__ oa2,
    int2* __restrict__ sedge) {
  int t = blockIdx.x * 256 + threadIdx.x;
  if (t >= K4_T) return;
  int4 s0 = ((const int4*)src)[t * 2],  s1 = ((const int4*)src)[t * 2 + 1];
  int4 d0 = ((const int4*)dstp)[t * 2], d1 = ((const int4*)dstp)[t * 2 + 1];
  int4 r0 = ((const int4*)rank)[t * 2], r1 = ((const int4*)rank)[t * 2 + 1];
  float A[8];
  A[0] = a1[s0.x]; A[1] = a1[s0.y]; A[2] = a1[s0.z]; A[3] = a1[s0.w];
  A[4] = a1[s1.x]; A[5] = a1[s1.y]; A[6] = a1[s1.z]; A[7] = a1[s1.w];
  int2 O[8];
  O[0] = oa2[d0.x]; O[1] = oa2[d0.y]; O[2] = oa2[d0.z]; O[3] = oa2[d0.w];
  O[4] = oa2[d1.x]; O[5] = oa2[d1.y]; O[6] = oa2[d1.z]; O[7] = oa2[d1.w];
  int S[8] = {s0.x, s0.y, s0.z, s0.w, s1.x, s1.y, s1.z, s1.w};
  int R[8] = {r0.x, r0.y, r0.z, r0.w, r1.x, r1.y, r1.z, r1.w};
#pragma unroll
  for (int q = 0; q < 8; ++q) {
    float e = A[q] + __int_as_float(O[q].y);
    e = e > 0.f ? e : 0.2f * e;  // leaky_relu 0.2
    // logits O(1): exp w/o max pass (softmax shift-invariant)
    sedge[O[q].x + R[q]] = make_int2(S[q], __float_as_int(__expf(e)));
  }
}

// ---------------------------------------------------------------------------
// K5: per-node weighted aggregation + ELU. 8 lanes/node (uint4/lane),
// 8 nodes/wave, 4-edge unroll -> 32 row-gathers in flight per wave.
// ---------------------------------------------------------------------------
__global__ __launch_bounds__(256) void k5_agg(
    const int* __restrict__ off, const int2* __restrict__ sedge,
    const __half* __restrict__ h, float* __restrict__ out) {
  int tid = threadIdx.x;
  int g = tid >> 3, gl = tid & 7;
  int n = blockIdx.x * 32 + g;
  if (n >= N_NODES) return;
  int b = off[n], e = off[n + 1];

  float sum = 0.f;
  float a0 = 0.f, a1_ = 0.f, a2_ = 0.f, a3 = 0.f;
  float a4 = 0.f, a5 = 0.f, a6 = 0.f, a7 = 0.f;
  const __half* __restrict__ hb = h;

#define K5_ACC(rr, ww)                                                        \
  {                                                                           \
    float2 f;                                                                 \
    f = __half22float2(__builtin_bit_cast(__half2, rr.x));                    \
    a0 = fmaf(ww, f.x, a0); a1_ = fmaf(ww, f.y, a1_);                         \
    f = __half22float2(__builtin_bit_cast(__half2, rr.y));                    \
    a2_ = fmaf(ww, f.x, a2_); a3 = fmaf(ww, f.y, a3);                         \
    f = __half22float2(__builtin_bit_cast(__half2, rr.z));                    \
    a4 = fmaf(ww, f.x, a4); a5 = fmaf(ww, f.y, a5);                           \
    f = __half22float2(__builtin_bit_cast(__half2, rr.w));                    \
    a6 = fmaf(ww, f.x, a6); a7 = fmaf(ww, f.y, a7);                           \
  }

  int j = b;
  for (; j + 3 < e; j += 4) {
    int2 s0 = sedge[j], s1 = sedge[j + 1], s2 = sedge[j + 2], s3 = sedge[j + 3];
    uint4 r0 = ((const uint4*)(hb + (size_t)s0.x * OUT_DIM))[gl];
    uint4 r1 = ((const uint4*)(hb + (size_t)s1.x * OUT_DIM))[gl];
    uint4 r2 = ((const uint4*)(hb + (size_t)s2.x * OUT_DIM))[gl];
    uint4 r3 = ((const uint4*)(hb + (size_t)s3.x * OUT_DIM))[gl];
    float w0 = __int_as_float(s0.y), w1 = __int_as_float(s1.y);
    float w2 = __int_as_float(s2.y), w3 = __int_as_float(s3.y);
    sum += (w0 + w1) + (w2 + w3);
    K5_ACC(r0, w0); K5_ACC(r1, w1); K5_ACC(r2, w2); K5_ACC(r3, w3);
  }
  for (; j < e; ++j) {
    int2 s0 = sedge[j];
    uint4 r0 = ((const uint4*)(hb + (size_t)s0.x * OUT_DIM))[gl];
    float w0 = __int_as_float(s0.y);
    sum += w0;
    K5_ACC(r0, w0);
  }

  float inv = (e > b) ? 1.f / sum : 0.f;
  a0 *= inv; a1_ *= inv; a2_ *= inv; a3 *= inv;
  a4 *= inv; a5 *= inv; a6 *= inv; a7 *= inv;
  float4 o0, o1;
  o0.x = a0 > 0.f ? a0 : (__expf(a0) - 1.f);
  o0.y = a1_ > 0.f ? a1_ : (__expf(a1_) - 1.f);
  o0.z = a2_ > 0.f ? a2_ : (__expf(a2_) - 1.f);
  o0.w = a3 > 0.f ? a3 : (__expf(a3) - 1.f);
  o1.x = a4 > 0.f ? a4 : (__expf(a4) - 1.f);
  o1.y = a5 > 0.f ? a5 : (__expf(a5) - 1.f);
  o1.z = a6 > 0.f ? a6 : (__expf(a6) - 1.f);
  o1.w = a7 > 0.f ? a7 : (__expf(a7) - 1.f);
  float4* ob = (float4*)(out + (size_t)n * OUT_DIM);
  ob[gl * 2] = o0;
  ob[gl * 2 + 1] = o1;
}

// ---------------------------------------------------------------------------
extern "C" void kernel_launch(void* const* d_in, const int* in_sizes, int n_in,
                              void* d_out, int out_size, void* d_ws, size_t ws_size,
                              hipStream_t stream) {
  const float* x   = (const float*)d_in[0];
  const int*   ei  = (const int*)d_in[1];   // [2, E]
  const float* W   = (const float*)d_in[2];
  const float* att = (const float*)d_in[3];
  float* out = (float*)d_out;

  char* p = (char*)d_ws;
  __half* h  = (__half*)p;  p += (size_t)N_NODES * OUT_DIM * sizeof(__half);  // 6.4 MB
  float* a1  = (float*)p;   p += (size_t)N_NODES * sizeof(float);
  float* a2  = (float*)p;   p += (size_t)N_NODES * sizeof(float);
  int*   deg = (int*)p;     p += (size_t)N_NODES * sizeof(int);
  int*   off = (int*)p;     p += (size_t)(N_NODES + 4) * sizeof(int);
  int2*  oa2 = (int2*)p;    p += (size_t)N_NODES * sizeof(int2);
  int*   rank = (int*)p;    p += (size_t)N_EDGES * sizeof(int);               // 3.2 MB
  int2*  sedge = (int2*)p;  p += (size_t)N_EDGES * sizeof(int2);              // 6.4 MB
  int*   bsum = (int*)p;    p += 64 * sizeof(int);

  const int* src  = ei;
  const int* dstp = ei + N_EDGES;

  k0_zero<<<SCAN_NB, 256, 0, stream>>>(deg);
  k12_fused<<<GEMM_NB, 256, 0, stream>>>(x, W, att, dstp, h, a1, a2, deg, rank);
  k3a_scan<<<SCAN_NB, 256, 0, stream>>>(deg, off, bsum);
  k3c_add<<<SCAN_NB, 256, 0, stream>>>(off, bsum, a2, oa2);
  k4_scatter<<<(K4_T + 255) / 256, 256, 0, stream>>>(src, dstp, rank, a1, oa2, sedge);
  k5_agg<<<(N_NODES + 31) / 32, 256, 0, stream>>>(off, sedge, h, out);
}